// Round 16
// baseline (86.660 us; speedup 1.0000x reference)
//
#include <hip/hip_runtime.h>

#define S_LEN 4096
#define B_SZ 8
#define HN_OFF 8388608      // 8*4096*256
#define CPROWS 544          // 8-elem rows per parity copy (zero-padded past 4096)

typedef __attribute__((ext_vector_type(8))) short short8;
typedef __attribute__((ext_vector_type(4))) float f32x4;

typedef const __attribute__((address_space(1))) unsigned int as1_u32;
typedef __attribute__((address_space(3))) unsigned int as3_u32;

__device__ __forceinline__ void gload16(const short* g, short* l) {
  __builtin_amdgcn_global_load_lds((as1_u32*)g, (as3_u32*)l, 16, 0, 0);
}

__device__ __forceinline__ short f2bf(float f) {
  union { float f; unsigned u; } v; v.f = f;
  unsigned r = v.u + 0x7FFFu + ((v.u >> 16) & 1u);
  return (short)(r >> 16);
}

#define MFMA(d, a, bb) d = __builtin_amdgcn_mfma_f32_16x16x32_bf16(a, bb, d, 0, 0, 0)

// K1 fused prep (R13, unchanged):
__global__ __launch_bounds__(256) void k_prep(const float* __restrict__ x,
                                              const float* __restrict__ Wu,
                                              const float* __restrict__ bu,
                                              const float* __restrict__ H,
                                              const float* __restrict__ Wh,
                                              short* __restrict__ cp,
                                              short* __restrict__ xb,
                                              short* __restrict__ Ht,
                                              short* __restrict__ wht) {
  int bx = blockIdx.x;
  if (bx >= 8520) {
    int j = (bx - 8520) * 256 + threadIdx.x;
    if (j < 256 * 384) {
      int n = j / 384, k = j % 384;
      wht[j] = f2bf(Wh[k * 256 + n]);
    }
    return;
  }
  if (bx >= 8264) {
    __shared__ short tile[64][72];
    int bx2 = bx - 8264;                 // 256 = tt(64) * qt(4)
    int t0 = (bx2 >> 2) << 6, q0 = (bx2 & 3) << 6;
    int tid = threadIdx.x;
    int r = tid >> 2, c0 = (tid & 3) << 4;
    const float* src = H + (size_t)(q0 + r) * S_LEN + t0 + c0;
    #pragma unroll
    for (int v4 = 0; v4 < 4; ++v4) {
      float4 hv = *(const float4*)(src + 4 * v4);
      tile[r][c0 + 4 * v4]     = f2bf(hv.x);
      tile[r][c0 + 4 * v4 + 1] = f2bf(hv.y);
      tile[r][c0 + 4 * v4 + 2] = f2bf(hv.z);
      tile[r][c0 + 4 * v4 + 3] = f2bf(hv.w);
    }
    __syncthreads();
    int s2 = tid >> 2, qc = (tid & 3) << 4;
    short8 o0, o1;
    #pragma unroll
    for (int j2 = 0; j2 < 8; ++j2) {
      o0[j2] = tile[qc + j2][s2];
      o1[j2] = tile[qc + 8 + j2][s2];
    }
    short* dst = Ht + (size_t)(t0 + s2) * 256 + q0 + qc;
    *(short8*)dst       = o0;
    *(short8*)(dst + 8) = o1;
    return;
  }
  if (bx >= 8192) {
    int idx = (bx - 8192) * 256 + threadIdx.x;
    if (idx < 18432) {
      int j = idx & 7;
      int r = 508 + ((idx >> 3) % 36);
      int rem = (idx >> 3) / 36;
      int p = rem & 7;
      int b = rem >> 3;
      int e = 8 * r + p + j;
      if (e >= S_LEN)
        cp[((size_t)(b * 8 + p) * CPROWS + r) * 8 + j] = 0;
    }
    return;
  }
  int row = bx * 4 + (threadIdx.x >> 6);   // b*4096 + t
  int l = threadIdx.x & 63;
  float2 xv = *(const float2*)(x + (size_t)row * 128 + 2 * l);
  float2 wv = *(const float2*)(Wu + 2 * l);
  float s = xv.x * wv.x + xv.y * wv.y;
  #pragma unroll
  for (int m = 32; m >= 1; m >>= 1) s += __shfl_xor(s, m, 64);
  unsigned pack = (((unsigned)f2bf(xv.y) & 0xFFFFu) << 16) | ((unsigned)f2bf(xv.x) & 0xFFFFu);
  *(unsigned*)(xb + (size_t)row * 128 + 2 * l) = pack;
  float v = s + bu[0];
  v = v > 0.0f ? v : 0.0f;
  short vb = f2bf(v);
  if (l < 8) {
    int t = row & (S_LEN - 1);
    int b = row >> 12;
    int e = (S_LEN - 1) - t;
    int p = l;
    if (e >= p) {
      int d = e - p;
      cp[((size_t)(b * 8 + p) * CPROWS + (d >> 3)) * 8 + (d & 7)] = vb;
    }
  }
}

// K2: Gt[n][t] = sum_q Wh[q,n]*H[q,t] (R13, unchanged)
__global__ __launch_bounds__(256) void k_g(const short* __restrict__ wht,
                                           const short* __restrict__ Ht,
                                           short* __restrict__ Gt) {
  int nt = blockIdx.x & 1, tt = blockIdx.x >> 1;
  int n0 = nt << 7, t0 = tt << 7;
  int tid = threadIdx.x;
  int lane = tid & 63, wid = tid >> 6;
  int wr = wid >> 1, wc = wid & 1;
  int lm = lane & 15, kg = lane >> 4;

  const short* Abase = wht + (size_t)(n0 + wr * 64 + lm) * 384 + 8 * kg;
  const short* Bbase = Ht  + (size_t)(t0 + wc * 64 + lm) * 256 + 8 * kg;

  f32x4 acc[4][4];
  #pragma unroll
  for (int ii = 0; ii < 4; ++ii)
    #pragma unroll
    for (int jn = 0; jn < 4; ++jn)
      acc[ii][jn] = (f32x4){0.0f, 0.0f, 0.0f, 0.0f};

  #pragma unroll
  for (int c = 0; c < 4; ++c) {
    short8 a[8], bf[8];
    #pragma unroll
    for (int mf = 0; mf < 4; ++mf)
      #pragma unroll
      for (int ks = 0; ks < 2; ++ks)
        a[mf * 2 + ks] = *(const short8*)(Abase + mf * 16 * 384 + c * 64 + ks * 32);
    #pragma unroll
    for (int nf = 0; nf < 4; ++nf)
      #pragma unroll
      for (int ks = 0; ks < 2; ++ks)
        bf[nf * 2 + ks] = *(const short8*)(Bbase + nf * 16 * 256 + c * 64 + ks * 32);
    #pragma unroll
    for (int ks = 0; ks < 2; ++ks)
      #pragma unroll
      for (int mf = 0; mf < 4; ++mf)
        #pragma unroll
        for (int nf = 0; nf < 4; ++nf)
          MFMA(acc[mf][nf], a[mf * 2 + ks], bf[nf * 2 + ks]);
  }

  #pragma unroll
  for (int mf = 0; mf < 4; ++mf)
    #pragma unroll
    for (int nf = 0; nf < 4; ++nf)
      #pragma unroll
      for (int j = 0; j < 4; ++j) {
        int n = n0 + wr * 64 + mf * 16 + kg * 4 + j;
        int t = t0 + wc * 64 + nf * 16 + lm;
        Gt[(size_t)n * S_LEN + t] = f2bf(acc[mf][nf][j]);
      }
}

// K3 fused, 8-phase-style schedule (T3+T4 port):
// 256 blocks x 512 thr, block tile 128(s)x128(n), in-block tile pairing
// (st=31-kk then kk -> exactly 70 BK-64 steps/block). Ring-3 LDS 60KB ->
// 2 blocks/CU (4 waves/SIMD). Per step: counted vmcnt(3) (never 0 in main
// loop; 3 uniform loads/wave/step), 2 phases {ds_read frags || stage-part ->
// barrier -> setprio + 8 MFMA -> barrier}. A staged by all 8 waves with
// 32-lane-active gloads (vmcnt uniformity); slot(G,P) <- cp[parity P^(G&7)]
// [row asbase+G]. x-part = 2 drained tail steps (Whx frags from L2 regs).
__global__ __launch_bounds__(512, 4) void k_fused(const short* __restrict__ cp,
                                                  const short* __restrict__ Gt,
                                                  const short* __restrict__ xb,
                                                  const short* __restrict__ wht,
                                                  const float* __restrict__ bh,
                                                  float* __restrict__ out) {
  __shared__ __attribute__((aligned(16))) short Bt[3][128 * 64];  // 48 KB
  __shared__ __attribute__((aligned(16))) short Aw[3][2048];      // 12 KB

  int i = blockIdx.x;                 // 256 = kk(16) * nt(2) * b(8)
  int kk = i >> 4;
  int nt = (i >> 3) & 1;
  int b  = i & 7;
  int n0 = nt << 7;

  int tid = threadIdx.x;
  int lane = tid & 63, wid = tid >> 6;   // 8 waves
  int wr = wid >> 2, wc = wid & 3;       // wr: s-half(64); wc: n-quarter(32)
  int lm = lane & 15, kg = lane >> 4;
  int l3v = lane >> 3, l7 = lane & 7;
  int lm7 = lm & 7;

  // B staging bases: half h rows = h*64 + wid*8 + l3v; src col chunk (l7^l3v)
  const short* bS0 = Gt + (size_t)(n0 + wid * 8 + l3v) * S_LEN + ((l7 ^ l3v) << 3);
  const short* bS1 = Gt + (size_t)(n0 + 64 + wid * 8 + l3v) * S_LEN + ((l7 ^ l3v) << 3);

  // A staging (lanes<32, all 8 waves): G = wid*4 + (la>>3), P = la&7
  int la = lane & 31;
  int G7 = ((wid & 1) << 2) | (la >> 3);
  int apar = (la & 7) ^ G7;

  // A-frag swizzled read offsets (R10 exact)
  int dbase = 127 - 64 * wr - lm + 8 * kg;
  int aof[6];
  #pragma unroll
  for (int ii = 0; ii < 6; ++ii) {
    int d = (ii < 4) ? (dbase - 16 * ii) : (dbase + 96 - 16 * ii);
    aof[ii] = ((d & ~7) | ((d & 7) ^ ((d >> 3) & 7))) << 3;
  }
  // B-frag offsets [ks][nf], 64-tau rows (R10 pattern, wc*32)
  int bofk[2][2];
  #pragma unroll
  for (int ks = 0; ks < 2; ++ks)
    #pragma unroll
    for (int nf = 0; nf < 2; ++nf)
      bofk[ks][nf] = (wc * 32 + nf * 16 + lm) * 64 + (((ks << 5) + (kg << 3)) ^ (lm7 << 3));
  // x A-frag offsets [mf][ks]
  int xof[4][2];
  #pragma unroll
  for (int mf = 0; mf < 4; ++mf)
    #pragma unroll
    for (int ks = 0; ks < 2; ++ks)
      xof[mf][ks] = (wr * 64 + mf * 16 + lm) * 64 + (((ks << 5) + (kg << 3)) ^ (lm7 << 3));

  for (int ph = 0; ph < 2; ++ph) {
    int st = ph ? kk : (31 - kk);
    int s0 = st << 7;
    int asbase = 496 - 16 * st;
    const short* aSrc = cp + ((size_t)(b * 8 + apar) * CPROWS + asbase + ((wid & 1) ? 4 : 0) + (wid >> 1) * 8 + (la >> 3)) * 8;
    // NOTE: G = wid*4 + (la>>3) must equal row offset; rewrite directly:
    aSrc = cp + ((size_t)(b * 8 + apar) * CPROWS + asbase + wid * 4 + (la >> 3)) * 8;
    const short* xH0 = xb + (size_t)(b * S_LEN + s0 + wid * 8 + l3v) * 128 + ((l7 ^ l3v) << 3);
    const short* xH1 = xb + (size_t)(b * S_LEN + s0 + 64 + wid * 8 + l3v) * 128 + ((l7 ^ l3v) << 3);

    int T = 2 * st + 2;

    f32x4 acc[4][2];
    #pragma unroll
    for (int ii = 0; ii < 4; ++ii)
      #pragma unroll
      for (int jn = 0; jn < 2; ++jn)
        acc[ii][jn] = (f32x4){0.0f, 0.0f, 0.0f, 0.0f};

    auto STG_B = [&](int cc, int h, int slot) {
      gload16((h ? bS1 : bS0) + cc * 64, &Bt[slot][h * 4096 + wid * 512]);
    };
    auto STG_A = [&](int cc, int slot) {
      if (lane < 32) gload16(aSrc + cc * 64, &Aw[slot][wid * 256]);
      else { asm volatile("" ::: );
        // keep instruction wave-uniform: issue a dummy-masked load is not
        // needed -- the gload above executes wave-wide with exec mask.
      }
    };
    auto STG_X = [&](int xc, int h, int slot) {
      gload16((h ? xH1 : xH0) + xc * 64, &Bt[slot][h * 4096 + wid * 512]);
    };

    if (ph) asm volatile("s_waitcnt lgkmcnt(0)\n\ts_barrier" ::: "memory");

    // prologue: steps 0 and 1 fully staged (3 loads each)
    STG_B(0, 0, 0); STG_B(0, 1, 0); STG_A(0, 0);
    STG_B(1, 0, 1); STG_B(1, 1, 1); STG_A(1, 1);

    int cur = 0;
    for (int c = 0; c < T; ++c) {
      if (c + 1 < T) asm volatile("s_waitcnt vmcnt(3)\n\ts_barrier" ::: "memory");
      else           asm volatile("s_waitcnt vmcnt(0)\n\ts_barrier" ::: "memory");
      const short* AwB = &Aw[cur][0];
      const short* BtB = &Bt[cur][0];
      int tg = (cur >= 1) ? (cur - 1) : 2;
      // ---- phase 0 (ks=0) ----
      short8 A0 = *(const short8*)(AwB + aof[0]);
      short8 A1 = *(const short8*)(AwB + aof[1]);
      short8 A2 = *(const short8*)(AwB + aof[2]);
      short8 A3 = *(const short8*)(AwB + aof[3]);
      short8 B00 = *(const short8*)(BtB + bofk[0][0]);
      short8 B01 = *(const short8*)(BtB + bofk[0][1]);
      if (c + 2 < T) { STG_B(c + 2, 0, tg); STG_A(c + 2, tg); }
      asm volatile("s_barrier" ::: "memory");
      __builtin_amdgcn_s_setprio(1);
      MFMA(acc[0][0], A0, B00); MFMA(acc[0][1], A0, B01);
      MFMA(acc[1][0], A1, B00); MFMA(acc[1][1], A1, B01);
      MFMA(acc[2][0], A2, B00); MFMA(acc[2][1], A2, B01);
      MFMA(acc[3][0], A3, B00); MFMA(acc[3][1], A3, B01);
      __builtin_amdgcn_s_setprio(0);
      asm volatile("s_barrier" ::: "memory");
      // ---- phase 1 (ks=1) ----
      short8 A4 = *(const short8*)(AwB + aof[4]);
      short8 A5 = *(const short8*)(AwB + aof[5]);
      short8 B10 = *(const short8*)(BtB + bofk[1][0]);
      short8 B11 = *(const short8*)(BtB + bofk[1][1]);
      if (c + 2 < T) STG_B(c + 2, 1, tg);
      asm volatile("s_barrier" ::: "memory");
      __builtin_amdgcn_s_setprio(1);
      MFMA(acc[0][0], A4, B10); MFMA(acc[0][1], A4, B11);
      MFMA(acc[1][0], A5, B10); MFMA(acc[1][1], A5, B11);
      MFMA(acc[2][0], A0, B10); MFMA(acc[2][1], A0, B11);
      MFMA(acc[3][0], A1, B10); MFMA(acc[3][1], A1, B11);
      __builtin_amdgcn_s_setprio(0);
      asm volatile("s_barrier" ::: "memory");
      cur = (cur == 2) ? 0 : cur + 1;
    }

    // ---- x-part: 2 tail steps, staged into slots cur, cur+1 ----
    int sx0 = cur;
    int sx1 = (cur == 2) ? 0 : cur + 1;
    STG_X(0, 0, sx0); STG_X(0, 1, sx0);
    STG_X(1, 0, sx1); STG_X(1, 1, sx1);
    short8 Bx[2][2][2];
    #pragma unroll
    for (int xc = 0; xc < 2; ++xc)
      #pragma unroll
      for (int ks = 0; ks < 2; ++ks)
        #pragma unroll
        for (int nf = 0; nf < 2; ++nf)
          Bx[xc][ks][nf] = *(const short8*)(wht + (size_t)(n0 + wc * 32 + nf * 16 + lm) * 384 + 256 + xc * 64 + ks * 32 + kg * 8);
    asm volatile("s_waitcnt vmcnt(0) lgkmcnt(0)\n\ts_barrier" ::: "memory");
    #pragma unroll
    for (int xc = 0; xc < 2; ++xc) {
      const short* XB = &Bt[xc ? sx1 : sx0][0];
      short8 Ax[4][2];
      #pragma unroll
      for (int mf = 0; mf < 4; ++mf)
        #pragma unroll
        for (int ks = 0; ks < 2; ++ks)
          Ax[mf][ks] = *(const short8*)(XB + xof[mf][ks]);
      __builtin_amdgcn_s_setprio(1);
      #pragma unroll
      for (int ks = 0; ks < 2; ++ks)
        #pragma unroll
        for (int mf = 0; mf < 4; ++mf)
          #pragma unroll
          for (int nf = 0; nf < 2; ++nf)
            MFMA(acc[mf][nf], Ax[mf][ks], Bx[xc][ks][nf]);
      __builtin_amdgcn_s_setprio(0);
    }

    // Epilogue: bias + relu + f32 store (+ h_n for s==4095)
    #pragma unroll
    for (int mf = 0; mf < 4; ++mf)
      #pragma unroll
      for (int nf = 0; nf < 2; ++nf) {
        int n = n0 + wc * 32 + nf * 16 + lm;
        float bias = bh[n];
        #pragma unroll
        for (int j2 = 0; j2 < 4; ++j2) {
          int s = s0 + wr * 64 + mf * 16 + kg * 4 + j2;
          float v = acc[mf][nf][j2] + bias;
          v = v > 0.0f ? v : 0.0f;
          out[(size_t)(b * S_LEN + s) * 256 + n] = v;
          if (s == S_LEN - 1)
            out[HN_OFF + b * 256 + n] = v;
        }
      }
  }
}

extern "C" void kernel_launch(void* const* d_in, const int* in_sizes, int n_in,
                              void* d_out, int out_size, void* d_ws, size_t ws_size,
                              hipStream_t stream) {
  const float* x  = (const float*)d_in[0];
  const float* Wu = (const float*)d_in[1];
  const float* bu = (const float*)d_in[2];
  const float* Wh = (const float*)d_in[3];
  const float* bh = (const float*)d_in[4];
  const float* H  = (const float*)d_in[5];
  float* out = (float*)d_out;

  char* ws = (char*)d_ws;
  short* cp  = (short*)(ws);                       // 557056 B
  short* wht = (short*)(ws + 557056);              // 196608 B
  short* xb  = (short*)(ws + 753664);              // 8388608 B
  short* Ht  = (short*)(ws + 9142272);             // 2097152 B
  short* Gt  = (short*)(ws + 11239424);            // 2097152 B (end 13336576)

  k_prep<<<8904, 256, 0, stream>>>(x, Wu, bu, H, Wh, cp, xb, Ht, wht);
  k_g   <<<64,   256, 0, stream>>>(wht, Ht, Gt);
  k_fused<<<256, 512, 0, stream>>>(cp, Gt, xb, wht, bh, out);
}

// Round 17
// 67.122 us; speedup vs baseline: 1.2911x; 1.2911x over previous
//
#include <hip/hip_runtime.h>

#define S_LEN 4096
#define B_SZ 8
#define HN_OFF 8388608      // 8*4096*256
#define CPROWS 544          // 8-elem rows per parity copy (zero-padded past 4096)

typedef __attribute__((ext_vector_type(8))) short short8;
typedef __attribute__((ext_vector_type(4))) float f32x4;

typedef const __attribute__((address_space(1))) unsigned int as1_u32;
typedef __attribute__((address_space(3))) unsigned int as3_u32;

__device__ __forceinline__ void gload16(const short* g, short* l) {
  __builtin_amdgcn_global_load_lds((as1_u32*)g, (as3_u32*)l, 16, 0, 0);
}

__device__ __forceinline__ short f2bf(float f) {
  union { float f; unsigned u; } v; v.f = f;
  unsigned r = v.u + 0x7FFFu + ((v.u >> 16) & 1u);
  return (short)(r >> 16);
}

#define MFMA(d, a, bb) d = __builtin_amdgcn_mfma_f32_16x16x32_bf16(a, bb, d, 0, 0, 0)

// K1 fused prep (R13, unchanged):
__global__ __launch_bounds__(256) void k_prep(const float* __restrict__ x,
                                              const float* __restrict__ Wu,
                                              const float* __restrict__ bu,
                                              const float* __restrict__ H,
                                              const float* __restrict__ Wh,
                                              short* __restrict__ cp,
                                              short* __restrict__ xb,
                                              short* __restrict__ Ht,
                                              short* __restrict__ wht) {
  int bx = blockIdx.x;
  if (bx >= 8520) {
    int j = (bx - 8520) * 256 + threadIdx.x;
    if (j < 256 * 384) {
      int n = j / 384, k = j % 384;
      wht[j] = f2bf(Wh[k * 256 + n]);
    }
    return;
  }
  if (bx >= 8264) {
    __shared__ short tile[64][72];
    int bx2 = bx - 8264;                 // 256 = tt(64) * qt(4)
    int t0 = (bx2 >> 2) << 6, q0 = (bx2 & 3) << 6;
    int tid = threadIdx.x;
    int r = tid >> 2, c0 = (tid & 3) << 4;
    const float* src = H + (size_t)(q0 + r) * S_LEN + t0 + c0;
    #pragma unroll
    for (int v4 = 0; v4 < 4; ++v4) {
      float4 hv = *(const float4*)(src + 4 * v4);
      tile[r][c0 + 4 * v4]     = f2bf(hv.x);
      tile[r][c0 + 4 * v4 + 1] = f2bf(hv.y);
      tile[r][c0 + 4 * v4 + 2] = f2bf(hv.z);
      tile[r][c0 + 4 * v4 + 3] = f2bf(hv.w);
    }
    __syncthreads();
    int s2 = tid >> 2, qc = (tid & 3) << 4;
    short8 o0, o1;
    #pragma unroll
    for (int j2 = 0; j2 < 8; ++j2) {
      o0[j2] = tile[qc + j2][s2];
      o1[j2] = tile[qc + 8 + j2][s2];
    }
    short* dst = Ht + (size_t)(t0 + s2) * 256 + q0 + qc;
    *(short8*)dst       = o0;
    *(short8*)(dst + 8) = o1;
    return;
  }
  if (bx >= 8192) {
    int idx = (bx - 8192) * 256 + threadIdx.x;
    if (idx < 18432) {
      int j = idx & 7;
      int r = 508 + ((idx >> 3) % 36);
      int rem = (idx >> 3) / 36;
      int p = rem & 7;
      int b = rem >> 3;
      int e = 8 * r + p + j;
      if (e >= S_LEN)
        cp[((size_t)(b * 8 + p) * CPROWS + r) * 8 + j] = 0;
    }
    return;
  }
  int row = bx * 4 + (threadIdx.x >> 6);   // b*4096 + t
  int l = threadIdx.x & 63;
  float2 xv = *(const float2*)(x + (size_t)row * 128 + 2 * l);
  float2 wv = *(const float2*)(Wu + 2 * l);
  float s = xv.x * wv.x + xv.y * wv.y;
  #pragma unroll
  for (int m = 32; m >= 1; m >>= 1) s += __shfl_xor(s, m, 64);
  unsigned pack = (((unsigned)f2bf(xv.y) & 0xFFFFu) << 16) | ((unsigned)f2bf(xv.x) & 0xFFFFu);
  *(unsigned*)(xb + (size_t)row * 128 + 2 * l) = pack;
  float v = s + bu[0];
  v = v > 0.0f ? v : 0.0f;
  short vb = f2bf(v);
  if (l < 8) {
    int t = row & (S_LEN - 1);
    int b = row >> 12;
    int e = (S_LEN - 1) - t;
    int p = l;
    if (e >= p) {
      int d = e - p;
      cp[((size_t)(b * 8 + p) * CPROWS + (d >> 3)) * 8 + (d & 7)] = vb;
    }
  }
}

// K2: Gt[n][t] = sum_q Wh[q,n]*H[q,t] (R13, unchanged)
__global__ __launch_bounds__(256) void k_g(const short* __restrict__ wht,
                                           const short* __restrict__ Ht,
                                           short* __restrict__ Gt) {
  int nt = blockIdx.x & 1, tt = blockIdx.x >> 1;
  int n0 = nt << 7, t0 = tt << 7;
  int tid = threadIdx.x;
  int lane = tid & 63, wid = tid >> 6;
  int wr = wid >> 1, wc = wid & 1;
  int lm = lane & 15, kg = lane >> 4;

  const short* Abase = wht + (size_t)(n0 + wr * 64 + lm) * 384 + 8 * kg;
  const short* Bbase = Ht  + (size_t)(t0 + wc * 64 + lm) * 256 + 8 * kg;

  f32x4 acc[4][4];
  #pragma unroll
  for (int ii = 0; ii < 4; ++ii)
    #pragma unroll
    for (int jn = 0; jn < 4; ++jn)
      acc[ii][jn] = (f32x4){0.0f, 0.0f, 0.0f, 0.0f};

  #pragma unroll
  for (int c = 0; c < 4; ++c) {
    short8 a[8], bf[8];
    #pragma unroll
    for (int mf = 0; mf < 4; ++mf)
      #pragma unroll
      for (int ks = 0; ks < 2; ++ks)
        a[mf * 2 + ks] = *(const short8*)(Abase + mf * 16 * 384 + c * 64 + ks * 32);
    #pragma unroll
    for (int nf = 0; nf < 4; ++nf)
      #pragma unroll
      for (int ks = 0; ks < 2; ++ks)
        bf[nf * 2 + ks] = *(const short8*)(Bbase + nf * 16 * 256 + c * 64 + ks * 32);
    #pragma unroll
    for (int ks = 0; ks < 2; ++ks)
      #pragma unroll
      for (int mf = 0; mf < 4; ++mf)
        #pragma unroll
        for (int nf = 0; nf < 4; ++nf)
          MFMA(acc[mf][nf], a[mf * 2 + ks], bf[nf * 2 + ks]);
  }

  #pragma unroll
  for (int mf = 0; mf < 4; ++mf)
    #pragma unroll
    for (int nf = 0; nf < 4; ++nf)
      #pragma unroll
      for (int j = 0; j < 4; ++j) {
        int n = n0 + wr * 64 + mf * 16 + kg * 4 + j;
        int t = t0 + wc * 64 + nf * 16 + lm;
        Gt[(size_t)n * S_LEN + t] = f2bf(acc[mf][nf][j]);
      }
}

// K3 fused: h[s,n] = relu(Toeplitz(u)@Gt^T + x@Whx + bh).
// 512 IDENTICAL blocks (kk,nq,b) x 4 waves: two tiles 128(s)x64(n)
// (st=31-kk then st=kk) -> every block 33 T-chunks (BK-128) + 4 x-chunks
// (BK-64). Equal blocks => any 2 co-resident blocks overlap end-to-end (the
// R3 fast regime), placement-independent. Ring-4 LDS 80KB -> 2 blocks/CU.
// R3 discipline: STAGE(c+2) before counted wait vmcnt(10/5/0)+lgkmcnt(0),
// one barrier/chunk. R13 BK-128 A algebra (aof[10] dedup). Uniform 5
// gloads/chunk (x-chunks carry one dummy A-gload).
__global__ __launch_bounds__(256, 2) void k_fused(const short* __restrict__ cp,
                                                  const short* __restrict__ Gt,
                                                  const short* __restrict__ xb,
                                                  const short* __restrict__ wht,
                                                  const float* __restrict__ bh,
                                                  float* __restrict__ out) {
  __shared__ __attribute__((aligned(16))) short Bt[4][64 * 128];  // 64 KB
  __shared__ __attribute__((aligned(16))) short Aw[4][2048];      // 16 KB

  int i = blockIdx.x;                 // 512 = kk(16) * nq(4) * b(8)
  int kk = i >> 5;
  int nq = (i >> 3) & 3;
  int b  = i & 7;
  int n0 = nq << 6;

  int tid = threadIdx.x;
  int lane = tid & 63, wid = tid >> 6;
  int wr = wid >> 1, wc = wid & 1;      // wave tile 64(s) x 32(n)
  int lm = lane & 15, kg = lane >> 4;
  int l3 = lane >> 3, l7 = lane & 7;
  int lm7 = lm & 7;

  // B staging (Gt rows n0..n0+63, 128-tau chunks): per wave 16 rows via 4
  // gloads of 4 rows (lane row = kg). Swizzle key = row&7 = 4j_odd + kg.
  const short* bS0 = Gt + (size_t)(n0 + wid * 16 + kg) * S_LEN + ((lm ^ kg) << 3);
  const short* bS1 = Gt + (size_t)(n0 + wid * 16 + 4 + kg) * S_LEN + ((lm ^ (kg | 4)) << 3);

  // A-frag swizzled offsets (R13 BK-128 dedup): frag(mf,ks) -> v = 2ks-mf+3
  int dbase = 127 - 64 * wr - lm + 8 * kg;
  int aof[10];
  #pragma unroll
  for (int v = 0; v < 10; ++v) {
    int d = dbase + 16 * v - 48;
    aof[v] = ((d & ~7) | ((d & 7) ^ ((d >> 3) & 7))) << 3;   // shorts
  }

  // B-frag offsets: row wc*32+nf*16+lm (nf 0..1), data chunk 4ks+kg, key lm7
  int bof[8];
  #pragma unroll
  for (int nf = 0; nf < 2; ++nf)
    #pragma unroll
    for (int ks = 0; ks < 4; ++ks)
      bof[nf * 4 + ks] = (wc * 32 + nf * 16 + lm) * 128 + (((4 * ks + kg) ^ lm7) << 3);

  // x A-frag offsets: row wr*64+mf*16+lm of [128 s][64 d] tile, chunk 4ks+kg
  int xof[4][2];
  #pragma unroll
  for (int mf = 0; mf < 4; ++mf)
    #pragma unroll
    for (int ks = 0; ks < 2; ++ks)
      xof[mf][ks] = (wr * 64 + mf * 16 + lm) * 64 + (((4 * ks + kg) ^ lm7) << 3);

  for (int ph = 0; ph < 2; ++ph) {
    int st = ph ? kk : (31 - kk);
    int s0 = st << 7;
    int asbase = 496 - 16 * st;
    const short* aSrc = cp + ((size_t)(b * 8 + (l7 ^ l3)) * CPROWS + asbase + wid * 8 + l3) * 8;
    // x staging: rows s0 + wid*32 + 8j + l3 of xb (row=128 shorts), key l3
    const short* xS = xb + (size_t)(b * S_LEN + s0 + wid * 32 + l3) * 128 + ((l7 ^ l3) << 3);

    int NT = st + 1;           // Toeplitz BK-128 chunks
    int NC = NT + 2;           // + 2 x BK-64 chunks

    f32x4 acc[4][2];
    #pragma unroll
    for (int ii = 0; ii < 4; ++ii)
      #pragma unroll
      for (int jn = 0; jn < 2; ++jn)
        acc[ii][jn] = (f32x4){0.0f, 0.0f, 0.0f, 0.0f};

    auto STAGE = [&](int cc) {
      int slot = cc & 3;
      if (cc < NT) {
        int coff = cc * 128;
        gload16(bS0 + coff,                      &Bt[slot][(wid * 16) * 128]);
        gload16(bS1 + coff,                      &Bt[slot][(wid * 16 + 4) * 128]);
        gload16(bS0 + (size_t)8 * S_LEN + coff,  &Bt[slot][(wid * 16 + 8) * 128]);
        gload16(bS1 + (size_t)8 * S_LEN + coff,  &Bt[slot][(wid * 16 + 12) * 128]);
        gload16(aSrc + coff,                     &Aw[slot][wid * 512]);
      } else {
        int dc = cc - NT;
        #pragma unroll
        for (int jj = 0; jj < 4; ++jj)
          gload16(xS + (size_t)(8 * jj) * 128 + dc * 64, &Bt[slot][(wid * 32 + 8 * jj) * 64]);
        gload16(aSrc, &Aw[slot][wid * 512]);   // dummy: uniform 5 loads/chunk
      }
    };

    if (ph) asm volatile("s_waitcnt vmcnt(0) lgkmcnt(0)\n\ts_barrier" ::: "memory");
    STAGE(0);
    STAGE(1);

    for (int c = 0; c < NC; ++c) {
      if (c + 2 < NC) {
        STAGE(c + 2);
        asm volatile("s_waitcnt vmcnt(10) lgkmcnt(0)\n\ts_barrier" ::: "memory");
      } else if (c + 1 < NC) {
        asm volatile("s_waitcnt vmcnt(5) lgkmcnt(0)\n\ts_barrier" ::: "memory");
      } else {
        asm volatile("s_waitcnt vmcnt(0) lgkmcnt(0)\n\ts_barrier" ::: "memory");
      }

      if (c < NT) {
        const short* AwB = &Aw[c & 3][0];
        const short* BtB = &Bt[c & 3][0];
        short8 A10[10];
        #pragma unroll
        for (int v = 0; v < 10; ++v) A10[v] = *(const short8*)(AwB + aof[v]);
        short8 Bf[8];
        #pragma unroll
        for (int ii = 0; ii < 8; ++ii) Bf[ii] = *(const short8*)(BtB + bof[ii]);
        __builtin_amdgcn_s_setprio(1);
        #pragma unroll
        for (int ks = 0; ks < 4; ++ks)
          #pragma unroll
          for (int mf = 0; mf < 4; ++mf)
            #pragma unroll
            for (int nf = 0; nf < 2; ++nf)
              MFMA(acc[mf][nf], A10[2 * ks - mf + 3], Bf[nf * 4 + ks]);
        __builtin_amdgcn_s_setprio(0);
      } else {
        int dc = c - NT;
        const short* BtB = &Bt[c & 3][0];
        short8 Ax[4][2];
        #pragma unroll
        for (int mf = 0; mf < 4; ++mf)
          #pragma unroll
          for (int ks = 0; ks < 2; ++ks)
            Ax[mf][ks] = *(const short8*)(BtB + xof[mf][ks]);
        short8 Bx[2][2];
        #pragma unroll
        for (int ks = 0; ks < 2; ++ks)
          #pragma unroll
          for (int nf = 0; nf < 2; ++nf)
            Bx[ks][nf] = *(const short8*)(wht + (size_t)(n0 + wc * 32 + nf * 16 + lm) * 384
                                          + 256 + dc * 64 + ks * 32 + kg * 8);
        __builtin_amdgcn_s_setprio(1);
        #pragma unroll
        for (int ks = 0; ks < 2; ++ks)
          #pragma unroll
          for (int mf = 0; mf < 4; ++mf)
            #pragma unroll
            for (int nf = 0; nf < 2; ++nf)
              MFMA(acc[mf][nf], Ax[mf][ks], Bx[ks][nf]);
        __builtin_amdgcn_s_setprio(0);
      }
    }

    // Epilogue: bias + relu + f32 store (+ h_n for s==4095)
    #pragma unroll
    for (int mf = 0; mf < 4; ++mf)
      #pragma unroll
      for (int nf = 0; nf < 2; ++nf) {
        int n = n0 + wc * 32 + nf * 16 + lm;
        float bias = bh[n];
        #pragma unroll
        for (int j2 = 0; j2 < 4; ++j2) {
          int s = s0 + wr * 64 + mf * 16 + kg * 4 + j2;
          float v = acc[mf][nf][j2] + bias;
          v = v > 0.0f ? v : 0.0f;
          out[(size_t)(b * S_LEN + s) * 256 + n] = v;
          if (s == S_LEN - 1)
            out[HN_OFF + b * 256 + n] = v;
        }
      }
  }
}

extern "C" void kernel_launch(void* const* d_in, const int* in_sizes, int n_in,
                              void* d_out, int out_size, void* d_ws, size_t ws_size,
                              hipStream_t stream) {
  const float* x  = (const float*)d_in[0];
  const float* Wu = (const float*)d_in[1];
  const float* bu = (const float*)d_in[2];
  const float* Wh = (const float*)d_in[3];
  const float* bh = (const float*)d_in[4];
  const float* H  = (const float*)d_in[5];
  float* out = (float*)d_out;

  char* ws = (char*)d_ws;
  short* cp  = (short*)(ws);                       // 557056 B
  short* wht = (short*)(ws + 557056);              // 196608 B
  short* xb  = (short*)(ws + 753664);              // 8388608 B
  short* Ht  = (short*)(ws + 9142272);             // 2097152 B
  short* Gt  = (short*)(ws + 11239424);            // 2097152 B (end 13336576)

  k_prep<<<8904, 256, 0, stream>>>(x, Wu, bu, H, Wh, cp, xb, Ht, wht);
  k_g   <<<64,   256, 0, stream>>>(wht, Ht, Gt);
  k_fused<<<512, 256, 0, stream>>>(cp, Gt, xb, wht, bh, out);
}